// Round 6
// baseline (328.152 us; speedup 1.0000x reference)
//
#include <hip/hip_runtime.h>
#include <hip/hip_bf16.h>
#include <math.h>

#define N_NODES 50000
#define D 128
#define LN_EPS 1e-5f
#define NB 391            // ceil(50000/128): buckets of 128 dst nodes
#define CHUNK 4096        // edges per partition workgroup
#define GB 782            // gemm blocks (3128 wave-slots for 3125 row-blocks)
#define HB 512            // hist blocks fused behind gemm

typedef unsigned int u32;
typedef unsigned short u16;
typedef __attribute__((ext_vector_type(8))) short bf16x8;
typedef __attribute__((ext_vector_type(4))) float f32x4;

static __device__ __forceinline__ u16 f2bf(float f) {   // RNE f32->bf16
    union { float f; unsigned u; } v; v.f = f;
    unsigned r = v.u + 0x7fff + ((v.u >> 16) & 1);
    return (u16)(r >> 16);
}
static __device__ __forceinline__ float bf2f(u16 b) {
    union { unsigned u; float f; } v; v.u = ((unsigned)b) << 16;
    return v.f;
}
static __device__ __forceinline__ bf16x8 packf8(const float* p) {
    float4 f0 = *(const float4*)p;
    float4 f1 = *(const float4*)(p + 4);
    bf16x8 r;
    r[0] = (short)f2bf(f0.x); r[1] = (short)f2bf(f0.y);
    r[2] = (short)f2bf(f0.z); r[3] = (short)f2bf(f0.w);
    r[4] = (short)f2bf(f1.x); r[5] = (short)f2bf(f1.y);
    r[6] = (short)f2bf(f1.z); r[7] = (short)f2bf(f1.w);
    return r;
}

// ---- shared agg core: gather-accumulate one node's 4 features/lane ----
static __device__ __forceinline__ void agg_core(
        const u16* __restrict__ H, const int2* __restrict__ csr,
        int s, int cnt, int c0,
        float& a0, float& a1, float& a2, float& a3) {
    float b0 = 0.f, b1 = 0.f, b2 = 0.f, b3 = 0.f;
    a0 = a1 = a2 = a3 = 0.f;
    const int2* ce = csr + s;
    int j = 0;
    for (; j + 8 <= cnt; j += 8) {
        int2 e0 = ce[j],     e1 = ce[j + 1], e2 = ce[j + 2], e3 = ce[j + 3];
        int2 e4 = ce[j + 4], e5 = ce[j + 5], e6 = ce[j + 6], e7 = ce[j + 7];
        ushort4 g0 = *(const ushort4*)&H[(size_t)(u32)e0.x * D + c0];
        ushort4 g1 = *(const ushort4*)&H[(size_t)(u32)e1.x * D + c0];
        ushort4 g2 = *(const ushort4*)&H[(size_t)(u32)e2.x * D + c0];
        ushort4 g3 = *(const ushort4*)&H[(size_t)(u32)e3.x * D + c0];
        ushort4 g4 = *(const ushort4*)&H[(size_t)(u32)e4.x * D + c0];
        ushort4 g5 = *(const ushort4*)&H[(size_t)(u32)e5.x * D + c0];
        ushort4 g6 = *(const ushort4*)&H[(size_t)(u32)e6.x * D + c0];
        ushort4 g7 = *(const ushort4*)&H[(size_t)(u32)e7.x * D + c0];
        float w0 = __int_as_float(e0.y), w1 = __int_as_float(e1.y);
        float w2 = __int_as_float(e2.y), w3 = __int_as_float(e3.y);
        float w4 = __int_as_float(e4.y), w5 = __int_as_float(e5.y);
        float w6 = __int_as_float(e6.y), w7 = __int_as_float(e7.y);
        a0 = fmaf(w0, bf2f(g0.x), a0); a1 = fmaf(w0, bf2f(g0.y), a1);
        a2 = fmaf(w0, bf2f(g0.z), a2); a3 = fmaf(w0, bf2f(g0.w), a3);
        b0 = fmaf(w1, bf2f(g1.x), b0); b1 = fmaf(w1, bf2f(g1.y), b1);
        b2 = fmaf(w1, bf2f(g1.z), b2); b3 = fmaf(w1, bf2f(g1.w), b3);
        a0 = fmaf(w2, bf2f(g2.x), a0); a1 = fmaf(w2, bf2f(g2.y), a1);
        a2 = fmaf(w2, bf2f(g2.z), a2); a3 = fmaf(w2, bf2f(g2.w), a3);
        b0 = fmaf(w3, bf2f(g3.x), b0); b1 = fmaf(w3, bf2f(g3.y), b1);
        b2 = fmaf(w3, bf2f(g3.z), b2); b3 = fmaf(w3, bf2f(g3.w), b3);
        a0 = fmaf(w4, bf2f(g4.x), a0); a1 = fmaf(w4, bf2f(g4.y), a1);
        a2 = fmaf(w4, bf2f(g4.z), a2); a3 = fmaf(w4, bf2f(g4.w), a3);
        b0 = fmaf(w5, bf2f(g5.x), b0); b1 = fmaf(w5, bf2f(g5.y), b1);
        b2 = fmaf(w5, bf2f(g5.z), b2); b3 = fmaf(w5, bf2f(g5.w), b3);
        a0 = fmaf(w6, bf2f(g6.x), a0); a1 = fmaf(w6, bf2f(g6.y), a1);
        a2 = fmaf(w6, bf2f(g6.z), a2); a3 = fmaf(w6, bf2f(g6.w), a3);
        b0 = fmaf(w7, bf2f(g7.x), b0); b1 = fmaf(w7, bf2f(g7.y), b1);
        b2 = fmaf(w7, bf2f(g7.z), b2); b3 = fmaf(w7, bf2f(g7.w), b3);
    }
    for (; j < cnt; ++j) {
        int2 e0 = ce[j];
        ushort4 g0 = *(const ushort4*)&H[(size_t)(u32)e0.x * D + c0];
        float w0 = __int_as_float(e0.y);
        a0 = fmaf(w0, bf2f(g0.x), a0); a1 = fmaf(w0, bf2f(g0.y), a1);
        a2 = fmaf(w0, bf2f(g0.z), a2); a3 = fmaf(w0, bf2f(g0.w), a3);
    }
    a0 += b0; a1 += b1; a2 += b2; a3 += b3;
}

// ---- shared LN+ELU (reduce within 32-lane half; 4 feats/lane) ----
static __device__ __forceinline__ void ln_elu(
        float& a0, float& a1, float& a2, float& a3, int c0,
        const float* __restrict__ bias, const float* __restrict__ gamma,
        const float* __restrict__ beta) {
    float4 bv = *(const float4*)&bias[c0];
    a0 += bv.x; a1 += bv.y; a2 += bv.z; a3 += bv.w;
    float sum = a0 + a1 + a2 + a3;
    float sq  = a0 * a0 + a1 * a1 + a2 * a2 + a3 * a3;
#pragma unroll
    for (int m = 16; m > 0; m >>= 1) {
        sum += __shfl_xor(sum, m, 64);
        sq  += __shfl_xor(sq,  m, 64);
    }
    float mean = sum * (1.f / 128.f);
    float var  = sq * (1.f / 128.f) - mean * mean;
    float rstd = rsqrtf(var + LN_EPS);
    float4 gv = *(const float4*)&gamma[c0];
    float4 ev = *(const float4*)&beta[c0];
    a0 = (a0 - mean) * rstd * gv.x + ev.x;
    a1 = (a1 - mean) * rstd * gv.y + ev.y;
    a2 = (a2 - mean) * rstd * gv.z + ev.z;
    a3 = (a3 - mean) * rstd * gv.w + ev.w;
    a0 = a0 > 0.f ? a0 : expm1f(a0);
    a1 = a1 > 0.f ? a1 : expm1f(a1);
    a2 = a2 > 0.f ? a2 : expm1f(a2);
    a3 = a3 > 0.f ? a3 : expm1f(a3);
}

// ---------- K1: gemm1 (blocks 0..GB-1) || bucket histogram (blocks GB..) ----------
__global__ __launch_bounds__(256) void gemm1_hist(const float* __restrict__ X,
                                                  const float* __restrict__ W,
                                                  u16* __restrict__ H,
                                                  const int* __restrict__ dstA,
                                                  u32* __restrict__ bucketCount, int E) {
    __shared__ __align__(16) u16 WT[D][136];
    __shared__ u32 hist[NB];

    if (blockIdx.x >= GB) {                     // ---- histogram part ----
        for (int b = threadIdx.x; b < NB; b += 256) hist[b] = 0;
        __syncthreads();
        int stride = HB * 256;
        for (int e = (blockIdx.x - GB) * 256 + threadIdx.x; e < E; e += stride)
            atomicAdd(&hist[((u32)dstA[e]) >> 7], 1u);
        __syncthreads();
        for (int b = threadIdx.x; b < NB; b += 256)
            if (hist[b]) atomicAdd(&bucketCount[b], hist[b]);
        return;
    }
    // ---- gemm part: H = bf16(X) @ bf16(W1) ----
    for (int idx = threadIdx.x; idx < D * D; idx += 256) {
        int k = idx >> 7, c = idx & 127;
        WT[c][k] = f2bf(W[idx]);
    }
    __syncthreads();

    int lane = threadIdx.x & 63;
    int wid  = threadIdx.x >> 6;
    int r    = lane & 15;
    int kg   = lane >> 4;

    for (int rb = blockIdx.x * 4 + wid; rb < N_NODES / 16; rb += GB * 4) {
        int row0 = rb * 16;
        const float* xp = X + (size_t)(row0 + r) * D + kg * 8;
        bf16x8 a0 = packf8(xp);      bf16x8 a1 = packf8(xp + 32);
        bf16x8 a2 = packf8(xp + 64); bf16x8 a3 = packf8(xp + 96);
#pragma unroll
        for (int tile = 0; tile < 8; ++tile) {
            const u16* wp = &WT[tile * 16 + r][kg * 8];
            f32x4 acc = {0.f, 0.f, 0.f, 0.f};
            acc = __builtin_amdgcn_mfma_f32_16x16x32_bf16(a0, *(const bf16x8*)(wp),      acc, 0, 0, 0);
            acc = __builtin_amdgcn_mfma_f32_16x16x32_bf16(a1, *(const bf16x8*)(wp + 32), acc, 0, 0, 0);
            acc = __builtin_amdgcn_mfma_f32_16x16x32_bf16(a2, *(const bf16x8*)(wp + 64), acc, 0, 0, 0);
            acc = __builtin_amdgcn_mfma_f32_16x16x32_bf16(a3, *(const bf16x8*)(wp + 96), acc, 0, 0, 0);
#pragma unroll
            for (int i = 0; i < 4; ++i)
                H[(size_t)(row0 + kg * 4 + i) * D + tile * 16 + r] = f2bf(acc[i]);
        }
    }
}

// ---------- K2: partition into bucket-dense packed array + per-node degree ----------
__global__ __launch_bounds__(512) void partition_kernel(const int* __restrict__ srcA,
                                                        const int* __restrict__ dstA,
                                                        const u32* __restrict__ bucketCount,
                                                        u32* __restrict__ relCursor,
                                                        u32* __restrict__ deg,
                                                        u32* __restrict__ ebuf, int E) {
    __shared__ u32 sc[512];
    __shared__ u32 ebS[NB], cntA[NB], cntB[NB], base[NB];
    int t = threadIdx.x;
    u32 bc = (t < NB) ? bucketCount[t] : 0u;
    sc[t] = bc;
    for (int b = t; b < NB; b += 512) { cntA[b] = 0; cntB[b] = 0; }
    __syncthreads();
    for (int off = 1; off < 512; off <<= 1) {        // inclusive scan
        u32 v = sc[t] + ((t >= off) ? sc[t - off] : 0u);
        __syncthreads();
        sc[t] = v;
        __syncthreads();
    }
    if (t < NB) ebS[t] = sc[t] - bc;                 // exclusive: edges before bucket
    __syncthreads();

    int e0 = blockIdx.x * CHUNK;
    int e1 = min(e0 + CHUNK, E);
    for (int e = e0 + t; e < e1; e += 512) {
        u32 d = (u32)dstA[e];
        atomicAdd(&cntA[d >> 7], 1u);
        atomicAdd(&deg[d], 1u);                      // per-node neighbor count
    }
    __syncthreads();
    for (int b = t; b < NB; b += 512)
        if (cntA[b]) base[b] = ebS[b] + atomicAdd(&relCursor[b], cntA[b]);
    __syncthreads();
    for (int e = e0 + t; e < e1; e += 512) {
        u32 d = (u32)dstA[e], sv = (u32)srcA[e];
        u32 b = d >> 7;
        u32 off = atomicAdd(&cntB[b], 1u);
        ebuf[base[b] + off] = (sv << 16) | d;        // src,dst < 65536
    }
}

// ---------- K3: per-bucket CSR build, single pass, premultiplied weights ----------
__global__ __launch_bounds__(256) void bucket_build(const u32* __restrict__ ebuf,
                                                    const u32* __restrict__ bucketCount,
                                                    const u32* __restrict__ deg,
                                                    int2* __restrict__ csr,
                                                    int* __restrict__ startArr) {
    int b = blockIdx.x, t = threadIdx.x;
    __shared__ u32 red[256];
    __shared__ u32 sc[128], cur[128];
    __shared__ float dloc[128];
    u32 partial = 0;                           // prefix of bucketCount over [0,b)
    for (int i = t; i < b; i += 256) partial += bucketCount[i];
    red[t] = partial;
    __syncthreads();
    for (int off = 128; off > 0; off >>= 1) {
        if (t < off) red[t] += red[t + off];
        __syncthreads();
    }
    u32 eb0 = red[0];                          // ebStart[b]
    u32 eb1 = eb0 + bucketCount[b];
    u32 cs  = eb0 + 128u * (u32)b;             // csrStart[b]

    int nodeBase = b << 7;
    int nNodes = min(128, N_NODES - nodeBase);
    u32 myCnt = 0;
    if (t < 128) {
        myCnt = (t < nNodes) ? deg[nodeBase + t] + 1u : 0u;   // +1 self-loop
        sc[t] = myCnt;
        dloc[t] = (t < nNodes) ? rsqrtf((float)myCnt) : 0.f;
    }
    __syncthreads();
    for (int off = 1; off < 128; off <<= 1) {  // inclusive scan
        u32 v = 0;
        if (t < 128) v = sc[t] + ((t >= off) ? sc[t - off] : 0u);
        __syncthreads();
        if (t < 128) sc[t] = v;
        __syncthreads();
    }
    if (t < nNodes) {
        u32 excl = sc[t] - myCnt;
        int i = nodeBase + t;
        startArr[i] = (int)(cs + excl);
        float di = dloc[t];
        int2 v; v.x = i; v.y = __float_as_int(di * di);
        csr[cs + excl] = v;                    // self-loop first
        cur[t] = excl + 1u;
        if (b == NB - 1 && t == nNodes - 1)
            startArr[N_NODES] = (int)(cs + sc[t]);
    }
    __syncthreads();
    for (u32 e = eb0 + t; e < eb1; e += 256) {
        u32 p = ebuf[e];
        u32 node = p & 127u;
        u32 src  = p >> 16;
        u32 pos = atomicAdd(&cur[node], 1u);
        float w = dloc[node] * rsqrtf((float)(deg[src] + 1u));
        int2 v; v.x = (int)src; v.y = __float_as_int(w);
        csr[cs + pos] = v;
    }
}

// ---------- K4: fused agg1 + bias/LN/ELU + GEMM2 (16 nodes/block, 512 thr) ----------
__global__ __launch_bounds__(512) void agg_gemm(
        const u16* __restrict__ H, const int2* __restrict__ csr,
        const int* __restrict__ startArr,
        const float* __restrict__ bias, const float* __restrict__ gamma,
        const float* __restrict__ beta,
        const float* __restrict__ W2, u16* __restrict__ H2) {
    __shared__ __align__(16) u16 WT[D][136];
    __shared__ __align__(16) u16 X2[16][136];

    int t = threadIdx.x;
    // stage W2^T (independent of agg phase; loads overlap)
    for (int idx = t; idx < D * D; idx += 512) {
        int k = idx >> 7, c = idx & 127;
        WT[c][k] = f2bf(W2[idx]);
    }

    // ---- agg phase: one node per 32-lane half ----
    int xr  = t >> 5;                          // 0..15: node slot in block
    int l   = t & 31;
    int c0  = l * 4;
    int node = blockIdx.x * 16 + xr;           // 3125 * 16 = 50000 exact
    int s   = startArr[node];
    int cnt = startArr[node + 1] - s;

    float a0, a1, a2, a3;
    agg_core(H, csr, s, cnt, c0, a0, a1, a2, a3);
    ln_elu(a0, a1, a2, a3, c0, bias, gamma, beta);

    ushort4 o;
    o.x = f2bf(a0); o.y = f2bf(a1); o.z = f2bf(a2); o.w = f2bf(a3);
    *(ushort4*)&X2[xr][c0] = o;
    __syncthreads();

    // ---- gemm phase: wave w computes col-tile w of rows [blk*16, +16) ----
    int lane = t & 63;
    int w    = t >> 6;                         // 8 waves = 8 col-tiles
    int r    = lane & 15;
    int kg   = lane >> 4;
    int row0 = blockIdx.x * 16;

    const u16* xp = &X2[r][kg * 8];
    bf16x8 a0f = *(const bf16x8*)(xp);
    bf16x8 a1f = *(const bf16x8*)(xp + 32);
    bf16x8 a2f = *(const bf16x8*)(xp + 64);
    bf16x8 a3f = *(const bf16x8*)(xp + 96);
    const u16* wp = &WT[w * 16 + r][kg * 8];
    f32x4 acc = {0.f, 0.f, 0.f, 0.f};
    acc = __builtin_amdgcn_mfma_f32_16x16x32_bf16(a0f, *(const bf16x8*)(wp),      acc, 0, 0, 0);
    acc = __builtin_amdgcn_mfma_f32_16x16x32_bf16(a1f, *(const bf16x8*)(wp + 32), acc, 0, 0, 0);
    acc = __builtin_amdgcn_mfma_f32_16x16x32_bf16(a2f, *(const bf16x8*)(wp + 64), acc, 0, 0, 0);
    acc = __builtin_amdgcn_mfma_f32_16x16x32_bf16(a3f, *(const bf16x8*)(wp + 96), acc, 0, 0, 0);
#pragma unroll
    for (int i = 0; i < 4; ++i)
        H2[(size_t)(row0 + kg * 4 + i) * D + w * 16 + r] = f2bf(acc[i]);
}

// ---------- K5: agg2 + bias/LN/ELU -> f32 out ----------
__global__ __launch_bounds__(256) void agg_ln_elu(
        const u16* __restrict__ H, const int2* __restrict__ csr,
        const int* __restrict__ startArr,
        const float* __restrict__ bias, const float* __restrict__ gamma,
        const float* __restrict__ beta, float* __restrict__ out) {
    int t = threadIdx.x;
    int node = blockIdx.x * 8 + (t >> 5);      // 6250 * 8 = 50000 exact
    int l    = t & 31;
    int c0   = l * 4;
    int s    = startArr[node];
    int cnt  = startArr[node + 1] - s;

    float a0, a1, a2, a3;
    agg_core(H, csr, s, cnt, c0, a0, a1, a2, a3);
    ln_elu(a0, a1, a2, a3, c0, bias, gamma, beta);

    f32x4 o = {a0, a1, a2, a3};
    __builtin_nontemporal_store(o, (f32x4*)(out + (size_t)node * D + c0));
}

// ---------------- launcher ----------------
extern "C" void kernel_launch(void* const* d_in, const int* in_sizes, int n_in,
                              void* d_out, int out_size, void* d_ws, size_t ws_size,
                              hipStream_t stream) {
    const float* x   = (const float*)d_in[0];
    const int*  eidx = (const int*)d_in[1];
    const float* W1  = (const float*)d_in[2];
    const float* b1  = (const float*)d_in[3];
    const float* g1  = (const float*)d_in[4];
    const float* be1 = (const float*)d_in[5];
    const float* W2  = (const float*)d_in[6];
    const float* b2  = (const float*)d_in[7];
    const float* g2  = (const float*)d_in[8];
    const float* be2 = (const float*)d_in[9];

    int E = in_sizes[1] / 2;
    const int* srcA = eidx;
    const int* dstA = eidx + E;

    char* p = (char*)d_ws;
    auto alloc = [&](size_t bytes) {
        char* r = p;
        p += (bytes + 255) & ~(size_t)255;
        return r;
    };
    u32*   zeroRegion = (u32*)alloc((size_t)(1024 + N_NODES) * 4);
    u32*   ebuf       = (u32*)alloc((size_t)E * 4);
    int2*  csr        = (int2*)alloc((size_t)(E + N_NODES) * 8);
    int*   startArr   = (int*)alloc((size_t)(N_NODES + 1) * 4);
    u16*   h          = (u16*)alloc((size_t)N_NODES * D * 2);
    u16*   h2         = (u16*)alloc((size_t)N_NODES * D * 2);
    float* outp       = (float*)d_out;

    u32* bucketCount = zeroRegion;
    u32* relCursor   = zeroRegion + 512;
    u32* deg         = zeroRegion + 1024;

    int pb = (E + CHUNK - 1) / CHUNK;          // 391 partition blocks
    int fb = N_NODES / 16;                     // 3125 fused agg+gemm blocks
    int ab = N_NODES / 8;                      // 6250 agg2 blocks

    hipError_t e0 = hipMemsetAsync(zeroRegion, 0, (size_t)(1024 + N_NODES) * 4, stream);
    (void)e0;
    gemm1_hist      <<<GB + HB, 256, 0, stream>>>(x, W1, h, dstA, bucketCount, E);
    partition_kernel<<<pb, 512, 0, stream>>>(srcA, dstA, bucketCount, relCursor, deg, ebuf, E);
    bucket_build    <<<NB, 256, 0, stream>>>(ebuf, bucketCount, deg, csr, startArr);
    agg_gemm        <<<fb, 512, 0, stream>>>(h, csr, startArr, b1, g1, be1, W2, h2);
    agg_ln_elu      <<<ab, 256, 0, stream>>>(h2, csr, startArr, b2, g2, be2, outp);
}

// Round 7
// 273.696 us; speedup vs baseline: 1.1990x; 1.1990x over previous
//
#include <hip/hip_runtime.h>
#include <hip/hip_bf16.h>
#include <math.h>

#define N_NODES 50000
#define D 128
#define LN_EPS 1e-5f
#define NB 391            // ceil(50000/128): buckets of 128 dst nodes
#define CHUNK 4096        // edges per partition workgroup
#define GB 782            // gemm blocks
#define HB 512            // hist blocks fused behind gemm

typedef unsigned int u32;
typedef unsigned short u16;
typedef __attribute__((ext_vector_type(8))) short bf16x8;
typedef __attribute__((ext_vector_type(8))) unsigned short u16x8;
typedef __attribute__((ext_vector_type(4))) float f32x4;

static __device__ __forceinline__ u16 f2bf(float f) {   // RNE f32->bf16
    union { float f; unsigned u; } v; v.f = f;
    unsigned r = v.u + 0x7fff + ((v.u >> 16) & 1);
    return (u16)(r >> 16);
}
static __device__ __forceinline__ float bf2f(u16 b) {
    union { unsigned u; float f; } v; v.u = ((unsigned)b) << 16;
    return v.f;
}
static __device__ __forceinline__ bf16x8 packf8(const float* p) {
    float4 f0 = *(const float4*)p;
    float4 f1 = *(const float4*)(p + 4);
    bf16x8 r;
    r[0] = (short)f2bf(f0.x); r[1] = (short)f2bf(f0.y);
    r[2] = (short)f2bf(f0.z); r[3] = (short)f2bf(f0.w);
    r[4] = (short)f2bf(f1.x); r[5] = (short)f2bf(f1.y);
    r[6] = (short)f2bf(f1.z); r[7] = (short)f2bf(f1.w);
    return r;
}

// ---- agg core: one node per 16-lane group, 8 feats/lane (ushort8 gathers) ----
static __device__ __forceinline__ void agg_core8(
        const u16* __restrict__ H, const u16* __restrict__ csr_src,
        const float* __restrict__ dinv, int s, int cnt, int c0, float dn,
        float* __restrict__ a) {
    float b[8];
#pragma unroll
    for (int i = 0; i < 8; ++i) { a[i] = 0.f; b[i] = 0.f; }
    const u16* cp = csr_src + s;
    int j = 0;
    for (; j + 8 <= cnt; j += 8) {
        u32 i0 = cp[j],     i1 = cp[j + 1], i2 = cp[j + 2], i3 = cp[j + 3];
        u32 i4 = cp[j + 4], i5 = cp[j + 5], i6 = cp[j + 6], i7 = cp[j + 7];
        u16x8 g0 = *(const u16x8*)&H[(size_t)i0 * D + c0];
        u16x8 g1 = *(const u16x8*)&H[(size_t)i1 * D + c0];
        u16x8 g2 = *(const u16x8*)&H[(size_t)i2 * D + c0];
        u16x8 g3 = *(const u16x8*)&H[(size_t)i3 * D + c0];
        u16x8 g4 = *(const u16x8*)&H[(size_t)i4 * D + c0];
        u16x8 g5 = *(const u16x8*)&H[(size_t)i5 * D + c0];
        u16x8 g6 = *(const u16x8*)&H[(size_t)i6 * D + c0];
        u16x8 g7 = *(const u16x8*)&H[(size_t)i7 * D + c0];
        float w0 = dinv[i0] * dn, w1 = dinv[i1] * dn;
        float w2 = dinv[i2] * dn, w3 = dinv[i3] * dn;
        float w4 = dinv[i4] * dn, w5 = dinv[i5] * dn;
        float w6 = dinv[i6] * dn, w7 = dinv[i7] * dn;
#pragma unroll
        for (int i = 0; i < 8; ++i) {
            a[i] = fmaf(w0, bf2f(g0[i]), a[i]);
            b[i] = fmaf(w1, bf2f(g1[i]), b[i]);
            a[i] = fmaf(w2, bf2f(g2[i]), a[i]);
            b[i] = fmaf(w3, bf2f(g3[i]), b[i]);
            a[i] = fmaf(w4, bf2f(g4[i]), a[i]);
            b[i] = fmaf(w5, bf2f(g5[i]), b[i]);
            a[i] = fmaf(w6, bf2f(g6[i]), a[i]);
            b[i] = fmaf(w7, bf2f(g7[i]), b[i]);
        }
    }
    for (; j < cnt; ++j) {
        u32 i0 = cp[j];
        u16x8 g0 = *(const u16x8*)&H[(size_t)i0 * D + c0];
        float w0 = dinv[i0] * dn;
#pragma unroll
        for (int i = 0; i < 8; ++i) a[i] = fmaf(w0, bf2f(g0[i]), a[i]);
    }
#pragma unroll
    for (int i = 0; i < 8; ++i) a[i] += b[i];
}

// ---- LN+ELU over 16-lane group, 8 feats/lane ----
static __device__ __forceinline__ void ln_elu8(
        float* __restrict__ a, int c0,
        const float* __restrict__ bias, const float* __restrict__ gamma,
        const float* __restrict__ beta) {
    float4 bv0 = *(const float4*)&bias[c0];
    float4 bv1 = *(const float4*)&bias[c0 + 4];
    a[0] += bv0.x; a[1] += bv0.y; a[2] += bv0.z; a[3] += bv0.w;
    a[4] += bv1.x; a[5] += bv1.y; a[6] += bv1.z; a[7] += bv1.w;
    float sum = 0.f, sq = 0.f;
#pragma unroll
    for (int i = 0; i < 8; ++i) { sum += a[i]; sq = fmaf(a[i], a[i], sq); }
#pragma unroll
    for (int m = 8; m > 0; m >>= 1) {          // reduce within 16-lane group
        sum += __shfl_xor(sum, m, 64);
        sq  += __shfl_xor(sq,  m, 64);
    }
    float mean = sum * (1.f / 128.f);
    float var  = sq * (1.f / 128.f) - mean * mean;
    float rstd = rsqrtf(var + LN_EPS);
    float4 gv0 = *(const float4*)&gamma[c0];
    float4 gv1 = *(const float4*)&gamma[c0 + 4];
    float4 ev0 = *(const float4*)&beta[c0];
    float4 ev1 = *(const float4*)&beta[c0 + 4];
    float gg[8] = {gv0.x, gv0.y, gv0.z, gv0.w, gv1.x, gv1.y, gv1.z, gv1.w};
    float ee[8] = {ev0.x, ev0.y, ev0.z, ev0.w, ev1.x, ev1.y, ev1.z, ev1.w};
#pragma unroll
    for (int i = 0; i < 8; ++i) {
        float y = (a[i] - mean) * rstd * gg[i] + ee[i];
        a[i] = y > 0.f ? y : expm1f(y);
    }
}

// ---------- K1: gemm1 (blocks 0..GB-1) || bucket histogram (blocks GB..) ----------
__global__ __launch_bounds__(256) void gemm1_hist(const float* __restrict__ X,
                                                  const float* __restrict__ W,
                                                  u16* __restrict__ H,
                                                  const int* __restrict__ dstA,
                                                  u32* __restrict__ bucketCount, int E) {
    __shared__ __align__(16) u16 WT[D][136];
    __shared__ u32 hist[NB];

    if (blockIdx.x >= GB) {                     // ---- histogram part ----
        for (int b = threadIdx.x; b < NB; b += 256) hist[b] = 0;
        __syncthreads();
        int stride = HB * 256;
        for (int e = (blockIdx.x - GB) * 256 + threadIdx.x; e < E; e += stride)
            atomicAdd(&hist[((u32)dstA[e]) >> 7], 1u);
        __syncthreads();
        for (int b = threadIdx.x; b < NB; b += 256)
            if (hist[b]) atomicAdd(&bucketCount[b], hist[b]);
        return;
    }
    // ---- gemm part: H = bf16(X) @ bf16(W1) ----
    for (int idx = threadIdx.x; idx < D * D; idx += 256) {
        int k = idx >> 7, c = idx & 127;
        WT[c][k] = f2bf(W[idx]);
    }
    __syncthreads();

    int lane = threadIdx.x & 63;
    int wid  = threadIdx.x >> 6;
    int r    = lane & 15;
    int kg   = lane >> 4;

    for (int rb = blockIdx.x * 4 + wid; rb < N_NODES / 16; rb += GB * 4) {
        int row0 = rb * 16;
        const float* xp = X + (size_t)(row0 + r) * D + kg * 8;
        bf16x8 a0 = packf8(xp);      bf16x8 a1 = packf8(xp + 32);
        bf16x8 a2 = packf8(xp + 64); bf16x8 a3 = packf8(xp + 96);
#pragma unroll
        for (int tile = 0; tile < 8; ++tile) {
            const u16* wp = &WT[tile * 16 + r][kg * 8];
            f32x4 acc = {0.f, 0.f, 0.f, 0.f};
            acc = __builtin_amdgcn_mfma_f32_16x16x32_bf16(a0, *(const bf16x8*)(wp),      acc, 0, 0, 0);
            acc = __builtin_amdgcn_mfma_f32_16x16x32_bf16(a1, *(const bf16x8*)(wp + 32), acc, 0, 0, 0);
            acc = __builtin_amdgcn_mfma_f32_16x16x32_bf16(a2, *(const bf16x8*)(wp + 64), acc, 0, 0, 0);
            acc = __builtin_amdgcn_mfma_f32_16x16x32_bf16(a3, *(const bf16x8*)(wp + 96), acc, 0, 0, 0);
#pragma unroll
            for (int i = 0; i < 4; ++i)
                H[(size_t)(row0 + kg * 4 + i) * D + tile * 16 + r] = f2bf(acc[i]);
        }
    }
}

// ---------- K2: partition edges into bucket-dense packed array ----------
__global__ __launch_bounds__(512) void partition_kernel(const int* __restrict__ srcA,
                                                        const int* __restrict__ dstA,
                                                        const u32* __restrict__ bucketCount,
                                                        u32* __restrict__ relCursor,
                                                        u32* __restrict__ ebuf, int E) {
    __shared__ u32 sc[512];
    __shared__ u32 ebS[NB], cntA[NB], cntB[NB], base[NB];
    int t = threadIdx.x;
    u32 bc = (t < NB) ? bucketCount[t] : 0u;
    sc[t] = bc;
    for (int b = t; b < NB; b += 512) { cntA[b] = 0; cntB[b] = 0; }
    __syncthreads();
    for (int off = 1; off < 512; off <<= 1) {        // inclusive scan
        u32 v = sc[t] + ((t >= off) ? sc[t - off] : 0u);
        __syncthreads();
        sc[t] = v;
        __syncthreads();
    }
    if (t < NB) ebS[t] = sc[t] - bc;                 // exclusive: edges before bucket
    __syncthreads();

    int e0 = blockIdx.x * CHUNK;
    int e1 = min(e0 + CHUNK, E);
    for (int e = e0 + t; e < e1; e += 512)
        atomicAdd(&cntA[((u32)dstA[e]) >> 7], 1u);
    __syncthreads();
    for (int b = t; b < NB; b += 512)
        if (cntA[b]) base[b] = ebS[b] + atomicAdd(&relCursor[b], cntA[b]);
    __syncthreads();
    for (int e = e0 + t; e < e1; e += 512) {
        u32 d = (u32)dstA[e], sv = (u32)srcA[e];
        u32 b = d >> 7;
        u32 off = atomicAdd(&cntB[b], 1u);
        ebuf[base[b] + off] = (sv << 16) | d;        // src,dst < 65536
    }
}

// ---------- K3: per-bucket CSR build (deg counted in LDS from ebuf) ----------
__global__ __launch_bounds__(256) void bucket_build(const u32* __restrict__ ebuf,
                                                    const u32* __restrict__ bucketCount,
                                                    u16* __restrict__ csr_src,
                                                    int* __restrict__ startArr,
                                                    float* __restrict__ dinv) {
    int b = blockIdx.x, t = threadIdx.x;
    __shared__ u32 red[256];
    __shared__ u32 cnt[128], sc[128], cur[128];
    u32 partial = 0;                           // prefix of bucketCount over [0,b)
    for (int i = t; i < b; i += 256) partial += bucketCount[i];
    red[t] = partial;
    if (t < 128) cnt[t] = 0;
    __syncthreads();
    for (int off = 128; off > 0; off >>= 1) {
        if (t < off) red[t] += red[t + off];
        __syncthreads();
    }
    u32 eb0 = red[0];                          // ebStart[b]
    u32 eb1 = eb0 + bucketCount[b];
    u32 cs  = eb0 + 128u * (u32)b;             // csrStart[b]

    int nodeBase = b << 7;
    int nNodes = min(128, N_NODES - nodeBase);
    for (u32 e = eb0 + t; e < eb1; e += 256)
        atomicAdd(&cnt[ebuf[e] & 127u], 1u);
    __syncthreads();
    u32 myCnt = 0;
    if (t < 128) {
        myCnt = (t < nNodes) ? cnt[t] + 1u : 0u;   // +1 self-loop
        sc[t] = myCnt;
    }
    __syncthreads();
    for (int off = 1; off < 128; off <<= 1) {  // inclusive scan
        u32 v = 0;
        if (t < 128) v = sc[t] + ((t >= off) ? sc[t - off] : 0u);
        __syncthreads();
        if (t < 128) sc[t] = v;
        __syncthreads();
    }
    if (t < nNodes) {
        u32 excl = sc[t] - myCnt;
        int i = nodeBase + t;
        startArr[i] = (int)(cs + excl);
        dinv[i] = rsqrtf((float)myCnt);
        csr_src[cs + excl] = (u16)i;           // self-loop first
        cur[t] = excl + 1u;
        if (b == NB - 1 && t == nNodes - 1)
            startArr[N_NODES] = (int)(cs + sc[t]);
    }
    __syncthreads();
    for (u32 e = eb0 + t; e < eb1; e += 256) {
        u32 p = ebuf[e];
        u32 pos = atomicAdd(&cur[p & 127u], 1u);
        csr_src[cs + pos] = (u16)(p >> 16);
    }
}

// ---------- K4: fused agg1 + bias/LN/ELU + GEMM2 (16 nodes/block, 256 thr) ----------
__global__ __launch_bounds__(256) void agg_gemm(
        const u16* __restrict__ H, const u16* __restrict__ csr_src,
        const int* __restrict__ startArr, const float* __restrict__ dinv,
        const float* __restrict__ bias, const float* __restrict__ gamma,
        const float* __restrict__ beta,
        const float* __restrict__ W2, u16* __restrict__ H2) {
    __shared__ __align__(16) u16 WT[D][136];
    __shared__ __align__(16) u16 X2[16][136];

    int t = threadIdx.x;
    for (int idx = t; idx < D * D; idx += 256) {   // stage W2^T (overlaps agg)
        int k = idx >> 7, c = idx & 127;
        WT[c][k] = f2bf(W2[idx]);
    }

    // ---- agg phase: one node per 16-lane group ----
    int grp = t >> 4;                          // 0..15 node slot
    int l   = t & 15;
    int c0  = l * 8;
    int node = blockIdx.x * 16 + grp;          // 3125 * 16 = 50000 exact
    int s   = startArr[node];
    int cnt = startArr[node + 1] - s;
    float dn = dinv[node];

    float a[8];
    agg_core8(H, csr_src, dinv, s, cnt, c0, dn, a);
    ln_elu8(a, c0, bias, gamma, beta);

    u16x8 o;
#pragma unroll
    for (int i = 0; i < 8; ++i) o[i] = f2bf(a[i]);
    *(u16x8*)&X2[grp][c0] = o;
    __syncthreads();

    // ---- gemm phase: 4 waves; wave w does col-tiles w and w+4 ----
    int lane = t & 63;
    int wv   = t >> 6;
    int r    = lane & 15;
    int kg   = lane >> 4;
    int row0 = blockIdx.x * 16;

    const u16* xp = &X2[r][kg * 8];
    bf16x8 a0f = *(const bf16x8*)(xp);
    bf16x8 a1f = *(const bf16x8*)(xp + 32);
    bf16x8 a2f = *(const bf16x8*)(xp + 64);
    bf16x8 a3f = *(const bf16x8*)(xp + 96);
#pragma unroll
    for (int tile = wv; tile < 8; tile += 4) {
        const u16* wp = &WT[tile * 16 + r][kg * 8];
        f32x4 acc = {0.f, 0.f, 0.f, 0.f};
        acc = __builtin_amdgcn_mfma_f32_16x16x32_bf16(a0f, *(const bf16x8*)(wp),      acc, 0, 0, 0);
        acc = __builtin_amdgcn_mfma_f32_16x16x32_bf16(a1f, *(const bf16x8*)(wp + 32), acc, 0, 0, 0);
        acc = __builtin_amdgcn_mfma_f32_16x16x32_bf16(a2f, *(const bf16x8*)(wp + 64), acc, 0, 0, 0);
        acc = __builtin_amdgcn_mfma_f32_16x16x32_bf16(a3f, *(const bf16x8*)(wp + 96), acc, 0, 0, 0);
#pragma unroll
        for (int i = 0; i < 4; ++i)
            H2[(size_t)(row0 + kg * 4 + i) * D + tile * 16 + r] = f2bf(acc[i]);
    }
}

// ---------- K5: agg2 + bias/LN/ELU -> f32 out (16 nodes/block) ----------
__global__ __launch_bounds__(256) void agg_ln_elu(
        const u16* __restrict__ H, const u16* __restrict__ csr_src,
        const int* __restrict__ startArr, const float* __restrict__ dinv,
        const float* __restrict__ bias, const float* __restrict__ gamma,
        const float* __restrict__ beta, float* __restrict__ out) {
    int t = threadIdx.x;
    int node = blockIdx.x * 16 + (t >> 4);     // 3125 * 16 = 50000 exact
    int l    = t & 15;
    int c0   = l * 8;
    int s    = startArr[node];
    int cnt  = startArr[node + 1] - s;
    float dn = dinv[node];

    float a[8];
    agg_core8(H, csr_src, dinv, s, cnt, c0, dn, a);
    ln_elu8(a, c0, bias, gamma, beta);

    f32x4 o0 = {a[0], a[1], a[2], a[3]};
    f32x4 o1 = {a[4], a[5], a[6], a[7]};
    float* op = out + (size_t)node * D + c0;
    __builtin_nontemporal_store(o0, (f32x4*)op);
    __builtin_nontemporal_store(o1, (f32x4*)(op + 4));
}

// ---------------- launcher ----------------
extern "C" void kernel_launch(void* const* d_in, const int* in_sizes, int n_in,
                              void* d_out, int out_size, void* d_ws, size_t ws_size,
                              hipStream_t stream) {
    const float* x   = (const float*)d_in[0];
    const int*  eidx = (const int*)d_in[1];
    const float* W1  = (const float*)d_in[2];
    const float* b1  = (const float*)d_in[3];
    const float* g1  = (const float*)d_in[4];
    const float* be1 = (const float*)d_in[5];
    const float* W2  = (const float*)d_in[6];
    const float* b2  = (const float*)d_in[7];
    const float* g2  = (const float*)d_in[8];
    const float* be2 = (const float*)d_in[9];

    int E = in_sizes[1] / 2;
    const int* srcA = eidx;
    const int* dstA = eidx + E;

    char* p = (char*)d_ws;
    auto alloc = [&](size_t bytes) {
        char* r = p;
        p += (bytes + 255) & ~(size_t)255;
        return r;
    };
    u32*   ctr      = (u32*)alloc((size_t)1024 * 4);   // bucketCount + relCursor
    u32*   ebuf     = (u32*)alloc((size_t)E * 4);
    u16*   csr_src  = (u16*)alloc((size_t)(E + N_NODES) * 2);
    int*   startArr = (int*)alloc((size_t)(N_NODES + 1) * 4);
    float* dinv     = (float*)alloc((size_t)N_NODES * 4);
    u16*   h        = (u16*)alloc((size_t)N_NODES * D * 2);
    u16*   h2       = (u16*)alloc((size_t)N_NODES * D * 2);
    float* outp     = (float*)d_out;

    u32* bucketCount = ctr;
    u32* relCursor   = ctr + 512;

    int pb = (E + CHUNK - 1) / CHUNK;          // 391 partition blocks
    int fb = N_NODES / 16;                     // 3125 blocks for both agg kernels

    hipError_t e0 = hipMemsetAsync(ctr, 0, 1024 * 4, stream);
    (void)e0;
    gemm1_hist      <<<GB + HB, 256, 0, stream>>>(x, W1, h, dstA, bucketCount, E);
    partition_kernel<<<pb, 512, 0, stream>>>(srcA, dstA, bucketCount, relCursor, ebuf, E);
    bucket_build    <<<NB, 256, 0, stream>>>(ebuf, bucketCount, csr_src, startArr, dinv);
    agg_gemm        <<<fb, 256, 0, stream>>>(h, csr_src, startArr, dinv,
                                             b1, g1, be1, W2, h2);
    agg_ln_elu      <<<fb, 256, 0, stream>>>(h2, csr_src, startArr, dinv,
                                             b2, g2, be2, outp);
}